// Round 3
// baseline (1216.536 us; speedup 1.0000x reference)
//
#include <hip/hip_runtime.h>
#include <math.h>

#define BB 2
#define CDIM 256
#define NHEADS 8
#define HD 32
#define HH 40
#define WW 40
#define NN 1600
#define C3 768
#define SCALE 0.17677669529663687f  // 1/sqrt(32)
#define RT 8            // rows per block in attention kernels
#define NRT (NN / RT)   // 200 row-tiles

// ---------- helpers ----------
__device__ inline unsigned fkey(float f) {
    unsigned u = __float_as_uint(f);
    return (u & 0x80000000u) ? ~u : (u | 0x80000000u);
}
__device__ inline float finv(unsigned u) {
    unsigned v = (u & 0x80000000u) ? (u ^ 0x80000000u) : ~u;
    return __uint_as_float(v);
}

// ---------- generic transpose: in[R][C] -> out[C][R] ----------
__global__ __launch_bounds__(256) void transpose_kernel(const float* __restrict__ in,
                                                        float* __restrict__ out,
                                                        int R, int C) {
    __shared__ float tile[32][33];
    int gx = (C + 31) / 32;
    int bx = blockIdx.x % gx, by = blockIdx.x / gx;
    int c0 = bx * 32, r0 = by * 32;
    int tx = threadIdx.x % 32, ty = threadIdx.x / 32;
#pragma unroll
    for (int dy = 0; dy < 4; dy++) {
        int r = r0 + ty + dy * 8, c = c0 + tx;
        if (r < R && c < C) tile[ty + dy * 8][tx] = in[(size_t)r * C + c];
    }
    __syncthreads();
#pragma unroll
    for (int dy = 0; dy < 4; dy++) {
        int c = c0 + ty + dy * 8, r = r0 + tx;
        if (r < R && c < C) out[(size_t)c * R + r] = tile[tx][ty + dy * 8];
    }
}

// ---------- 1x1 conv -> [b][s][c3] layout; wT is [ic][oc] ----------
__global__ __launch_bounds__(256) void conv1x1_kernel(const float* __restrict__ x,
                                                      const float* __restrict__ wT,
                                                      const float* __restrict__ bias,
                                                      float* __restrict__ out) {
    int blk = blockIdx.x;
    int s0 = (blk % 200) * 8;
    int b = blk / 200;
    int tid = threadIdx.x;
    float acc[3][8];
#pragma unroll
    for (int ch = 0; ch < 3; ch++) {
        float bv = bias[ch * 256 + tid];
#pragma unroll
        for (int i = 0; i < 8; i++) acc[ch][i] = bv;
    }
    const float* xb = x + (size_t)b * CDIM * NN + s0;
    for (int ic = 0; ic < CDIM; ic++) {
        float xv[8];
#pragma unroll
        for (int i = 0; i < 8; i++) xv[i] = xb[(size_t)ic * NN + i];
        const float* wr = wT + (size_t)ic * C3 + tid;
#pragma unroll
        for (int ch = 0; ch < 3; ch++) {
            float wv = wr[ch * 256];
#pragma unroll
            for (int i = 0; i < 8; i++) acc[ch][i] += wv * xv[i];
        }
    }
#pragma unroll
    for (int ch = 0; ch < 3; ch++)
#pragma unroll
        for (int i = 0; i < 8; i++)
            out[((size_t)b * NN + s0 + i) * C3 + ch * 256 + tid] = acc[ch][i];
}

// ---------- depthwise 3x3 pad1 in [b][s][c] layout; wT is [9][c3] ----------
__global__ __launch_bounds__(256) void dwconv_kernel(const float* __restrict__ in,
                                                     const float* __restrict__ wT,
                                                     const float* __restrict__ bias,
                                                     float* __restrict__ out) {
    int s = blockIdx.x % NN;
    int b = blockIdx.x / NN;
    int y = s / WW, x = s % WW;
    int tid = threadIdx.x;
#pragma unroll
    for (int ch = 0; ch < 3; ch++) {
        int c = ch * 256 + tid;
        float acc = bias[c];
#pragma unroll
        for (int ky = 0; ky < 3; ky++) {
            int iy = y + ky - 1;
            if (iy < 0 || iy >= HH) continue;
#pragma unroll
            for (int kx = 0; kx < 3; kx++) {
                int ix = x + kx - 1;
                if (ix < 0 || ix >= WW) continue;
                acc += wT[(ky * 3 + kx) * C3 + c] * in[((size_t)b * NN + iy * WW + ix) * C3 + c];
            }
        }
        out[((size_t)b * NN + s) * C3 + c] = acc;
    }
}

// ---------- phase 1: entropy, att in regs, no max-subtraction ----------
__global__ __launch_bounds__(256) void entropy_kernel(const float* __restrict__ qkvT,
                                                      float* __restrict__ ent) {
    int blk = blockIdx.x;      // bh*NRT + rt
    int rt = blk % NRT;
    int bh = blk / NRT;
    int h = bh % NHEADS, b = bh / NHEADS;
    int row0 = rt * RT;
    int tid = threadIdx.x;
    int w = __builtin_amdgcn_readfirstlane(tid >> 6);
    int lane = tid & 63;
    int lr0 = 2 * w, lr1 = lr0 + 1;
    // wave-uniform Q rows -> scalar regs
    const float* q0p = qkvT + ((size_t)b * NN + row0 + lr0) * C3 + h * HD;
    const float* q1p = q0p + C3;
    float q0[HD], q1[HD];
#pragma unroll
    for (int d = 0; d < HD; d++) { q0[d] = q0p[d]; q1[d] = q1p[d]; }
    const float* kb = qkvT + (size_t)b * NN * C3 + CDIM + h * HD;
    float S0 = 0.f, T0 = 0.f, S1 = 0.f, T1 = 0.f;
#pragma unroll
    for (int kt = 0; kt < 25; kt++) {
        int j = kt * 64 + lane;
        const float4* kp = (const float4*)(kb + (size_t)j * C3);
        float4 kv[8];
#pragma unroll
        for (int i = 0; i < 8; i++) kv[i] = kp[i];
        float a0 = 0.f, a1 = 0.f;
#pragma unroll
        for (int i = 0; i < 8; i++) {
            a0 += q0[4 * i] * kv[i].x + q0[4 * i + 1] * kv[i].y + q0[4 * i + 2] * kv[i].z + q0[4 * i + 3] * kv[i].w;
            a1 += q1[4 * i] * kv[i].x + q1[4 * i + 1] * kv[i].y + q1[4 * i + 2] * kv[i].z + q1[4 * i + 3] * kv[i].w;
        }
        a0 *= SCALE; a1 *= SCALE;
        float e0 = __expf(a0), e1 = __expf(a1);
        S0 += e0; T0 += e0 * a0;
        S1 += e1; T1 += e1 * a1;
    }
#pragma unroll
    for (int o = 1; o < 64; o <<= 1) {
        S0 += __shfl_xor(S0, o); T0 += __shfl_xor(T0, o);
        S1 += __shfl_xor(S1, o); T1 += __shfl_xor(T1, o);
    }
    if (lane == 0) {
        ent[(size_t)bh * NN + row0 + lr0] = logf(S0) - T0 / S0;
        ent[(size_t)bh * NN + row0 + lr1] = logf(S1) - T1 / S1;
    }
}

// ---------- gate ----------
__global__ void gate_kernel(const float* __restrict__ ent_rows,
                            const float* __restrict__ g1w, const float* __restrict__ g1b,
                            const float* __restrict__ g2w, const float* __restrict__ g2b,
                            int* __restrict__ keep) {
    int bh = blockIdx.x;
    int tid = threadIdx.x;
    __shared__ float red[4];
    float ls = 0.f;
    for (int j = tid; j < NN; j += 256) ls += ent_rows[bh * NN + j];
    for (int o = 32; o > 0; o >>= 1) ls += __shfl_down(ls, o);
    int lane = tid & 63, wid = tid >> 6;
    if (lane == 0) red[wid] = ls;
    __syncthreads();
    if (tid == 0) {
        float ent = (red[0] + red[1] + red[2] + red[3]) / (float)NN;
        float val = g2b[0];
#pragma unroll
        for (int j = 0; j < 16; j++) {
            float hid = ent * g1w[j] + g1b[j];
            if (hid < 0.f) hid = 0.f;
            val += hid * g2w[j];
        }
        float ratio = 0.9f / (1.f + expf(-val)) + 0.1f;
        int kp = (int)ceilf(ratio * (float)NN);
        if (kp < 1) kp = 1;
        if (kp > NN) kp = NN;
        keep[bh] = kp;
    }
}

// ---------- radix select kth-largest over one row held in regs (25 vals/lane) ----------
__device__ inline unsigned radix_select(const float (&av)[25], int wnt,
                                        unsigned* hist, int lane) {
    unsigned prefixHigh = 0;
    for (int pass = 0; pass < 4; pass++) {
        int shift = 24 - 8 * pass;
#pragma unroll
        for (int i = 0; i < 4; i++) hist[lane * 4 + i] = 0u;
#pragma unroll
        for (int kt = 0; kt < 25; kt++) {
            unsigned u = fkey(av[kt]);
            bool ok = (pass == 0) || ((u >> (shift + 8)) == prefixHigh);
            if (ok) atomicAdd(&hist[(u >> shift) & 255u], 1u);
        }
        unsigned sch = 0;
#pragma unroll
        for (int i = 0; i < 4; i++) sch += hist[255 - 4 * lane - i];
        unsigned inc = sch;
#pragma unroll
        for (int dlt = 1; dlt < 64; dlt <<= 1) {
            unsigned tv = __shfl_up(inc, dlt, 64);
            if (lane >= dlt) inc += tv;
        }
        unsigned pref = inc - sch;
        bool found = (pref < (unsigned)wnt) && ((unsigned)wnt <= inc);
        int bsel = -1, wnew = 0;
        if (found) {
            unsigned want2 = (unsigned)wnt - pref, cum = 0;
#pragma unroll
            for (int i = 0; i < 4; i++) {
                int bbin = 255 - 4 * lane - i;
                unsigned c = hist[bbin];
                if (bsel < 0 && cum + c >= want2) { bsel = bbin; wnew = (int)(want2 - cum); }
                cum += c;
            }
        }
        unsigned long long mk = __ballot(found);
        int src = __builtin_ctzll(mk);
        bsel = __shfl(bsel, src);
        wnt = __shfl(wnew, src);
        prefixHigh = (prefixHigh << 8) | (unsigned)bsel;
    }
    return prefixHigh;
}

// ---------- phase 2: att in regs, radix select, sparse softmax + PV ----------
__global__ __launch_bounds__(256) void sparse_attn_kernel(const float* __restrict__ qkvT,
                                                          const int* __restrict__ keep,
                                                          float* __restrict__ oh) {
    int blk = blockIdx.x;
    int rt = blk % NRT;
    int bh = blk / NRT;
    int h = bh % NHEADS, b = bh / NHEADS;
    int row0 = rt * RT;
    __shared__ unsigned histArr[4][256];
    __shared__ float scratch[4][2112];
    int tid = threadIdx.x;
    int w = __builtin_amdgcn_readfirstlane(tid >> 6);
    int lane = tid & 63;
    int lr0 = 2 * w, lr1 = lr0 + 1;
    // wave-uniform Q rows -> scalar regs
    const float* q0p = qkvT + ((size_t)b * NN + row0 + lr0) * C3 + h * HD;
    const float* q1p = q0p + C3;
    float q0[HD], q1[HD];
#pragma unroll
    for (int d = 0; d < HD; d++) { q0[d] = q0p[d]; q1[d] = q1p[d]; }
    const float* kb = qkvT + (size_t)b * NN * C3 + CDIM + h * HD;
    const float* vb = qkvT + (size_t)b * NN * C3 + 2 * CDIM + h * HD;

    // ---- QK^T into registers ----
    float av0[25], av1[25];
#pragma unroll
    for (int kt = 0; kt < 25; kt++) {
        int j = kt * 64 + lane;
        const float4* kp = (const float4*)(kb + (size_t)j * C3);
        float4 kv[8];
#pragma unroll
        for (int i = 0; i < 8; i++) kv[i] = kp[i];
        float a0 = 0.f, a1 = 0.f;
#pragma unroll
        for (int i = 0; i < 8; i++) {
            a0 += q0[4 * i] * kv[i].x + q0[4 * i + 1] * kv[i].y + q0[4 * i + 2] * kv[i].z + q0[4 * i + 3] * kv[i].w;
            a1 += q1[4 * i] * kv[i].x + q1[4 * i + 1] * kv[i].y + q1[4 * i + 2] * kv[i].z + q1[4 * i + 3] * kv[i].w;
        }
        av0[kt] = a0 * SCALE;
        av1[kt] = a1 * SCALE;
    }

    // ---- kth threshold per row (rows sequential on the full wave) ----
    int want = keep[bh];
    unsigned k0bits = radix_select(av0, want, &histArr[w][0], lane);
    unsigned k1bits = radix_select(av1, want, &histArr[w][0], lane);
    float kth0 = finv(k0bits), kth1 = finv(k1bits);

    // ---- sparse softmax weights (no max-sub; raw exp) ----
    float S0 = 0.f, S1 = 0.f;
#pragma unroll
    for (int kt = 0; kt < 25; kt++) {
        float p0 = (av0[kt] >= kth0) ? __expf(av0[kt]) : 0.f;
        float p1 = (av1[kt] >= kth1) ? __expf(av1[kt]) : 0.f;
        av0[kt] = p0; av1[kt] = p1;
        S0 += p0; S1 += p1;
    }
#pragma unroll
    for (int o = 1; o < 64; o <<= 1) {
        S0 += __shfl_xor(S0, o);
        S1 += __shfl_xor(S1, o);
    }

    // ---- PV ----
    float acc0[HD], acc1[HD];
#pragma unroll
    for (int d = 0; d < HD; d++) { acc0[d] = 0.f; acc1[d] = 0.f; }
#pragma unroll
    for (int kt = 0; kt < 25; kt++) {
        int j = kt * 64 + lane;
        const float4* vp = (const float4*)(vb + (size_t)j * C3);
        float4 vv[8];
#pragma unroll
        for (int i = 0; i < 8; i++) vv[i] = vp[i];
        float p0 = av0[kt], p1 = av1[kt];
#pragma unroll
        for (int i = 0; i < 8; i++) {
            acc0[4 * i] += p0 * vv[i].x; acc0[4 * i + 1] += p0 * vv[i].y;
            acc0[4 * i + 2] += p0 * vv[i].z; acc0[4 * i + 3] += p0 * vv[i].w;
            acc1[4 * i] += p1 * vv[i].x; acc1[4 * i + 1] += p1 * vv[i].y;
            acc1[4 * i + 2] += p1 * vv[i].z; acc1[4 * i + 3] += p1 * vv[i].w;
        }
    }

    // ---- reduce acc across 64 lanes via per-wave LDS scratch ----
    float* sc = &scratch[w][0];
    int dd = lane & 31;
    int jb = (lane < 32) ? 0 : 32;
#pragma unroll
    for (int d = 0; d < HD; d++) sc[lane * 33 + d] = acc0[d];
    float sum0 = 0.f;
#pragma unroll
    for (int jj = 0; jj < 32; jj++) sum0 += sc[(jb + jj) * 33 + dd];
    sum0 += __shfl_xor(sum0, 32);
#pragma unroll
    for (int d = 0; d < HD; d++) sc[lane * 33 + d] = acc1[d];
    float sum1 = 0.f;
#pragma unroll
    for (int jj = 0; jj < 32; jj++) sum1 += sc[(jb + jj) * 33 + dd];
    sum1 += __shfl_xor(sum1, 32);

    if (lane < 32) {
        size_t base = ((size_t)b * NN + row0) * CDIM + h * HD + dd;
        oh[base + (size_t)lr0 * CDIM] = sum0 / S0;
        oh[base + (size_t)lr1 * CDIM] = sum1 / S1;
    }
}

// ---------- output projection: oh [b][s][c] -> out [b][co][s]; wT is [c][co] ----------
__global__ __launch_bounds__(256) void proj_kernel(const float* __restrict__ oh,
                                                   const float* __restrict__ wT,
                                                   const float* __restrict__ pb,
                                                   float* __restrict__ out) {
    int blk = blockIdx.x;
    int s0 = (blk % 200) * 8;
    int b = blk / 200;
    int co = threadIdx.x;
    float acc[8];
    float bv = pb[co];
#pragma unroll
    for (int i = 0; i < 8; i++) acc[i] = bv;
    const float* ob = oh + ((size_t)b * NN + s0) * CDIM;
    for (int c = 0; c < CDIM; c++) {
        float wv = wT[(size_t)c * CDIM + co];
        float ov[8];
#pragma unroll
        for (int i = 0; i < 8; i++) ov[i] = ob[(size_t)i * CDIM + c];
#pragma unroll
        for (int i = 0; i < 8; i++) acc[i] += wv * ov[i];
    }
#pragma unroll
    for (int i = 0; i < 8; i++)
        out[((size_t)b * CDIM + co) * NN + s0 + i] = acc[i];
}

extern "C" void kernel_launch(void* const* d_in, const int* in_sizes, int n_in,
                              void* d_out, int out_size, void* d_ws, size_t ws_size,
                              hipStream_t stream) {
    const float* x      = (const float*)d_in[0];
    const float* qkv_w  = (const float*)d_in[1];
    const float* qkv_b  = (const float*)d_in[2];
    const float* pos_w  = (const float*)d_in[3];
    const float* pos_b  = (const float*)d_in[4];
    const float* proj_w = (const float*)d_in[5];
    const float* proj_b = (const float*)d_in[6];
    const float* g1w    = (const float*)d_in[7];
    const float* g1b    = (const float*)d_in[8];
    const float* g2w    = (const float*)d_in[9];
    const float* g2b    = (const float*)d_in[10];
    float* out = (float*)d_out;

    float* ws    = (float*)d_ws;
    float* wqT   = ws;                                   // 256*768
    float* wpT   = wqT + (size_t)CDIM * C3;              // 256*256
    float* wposT = wpT + (size_t)CDIM * CDIM;            // 9*768
    float* buf1  = wposT + (size_t)9 * C3;               // BB*NN*C3
    float* buf2  = buf1 + (size_t)BB * NN * C3;          // BB*NN*C3
    float* ent   = buf2 + (size_t)BB * NN * C3;          // BB*NHEADS*NN
    float* oh    = ent + (size_t)BB * NHEADS * NN;       // BB*NN*CDIM
    int* keep    = (int*)(oh + (size_t)BB * NN * CDIM);  // BB*NHEADS

    // weight transposes (tiny)
    transpose_kernel<<<8 * 24, 256, 0, stream>>>(qkv_w, wqT, C3, CDIM);   // [768][256]->[256][768]
    transpose_kernel<<<8 * 8, 256, 0, stream>>>(proj_w, wpT, CDIM, CDIM); // [256][256]->[256][256]
    transpose_kernel<<<1 * 24, 256, 0, stream>>>(pos_w, wposT, C3, 9);    // [768][9]->[9][768]

    conv1x1_kernel<<<BB * 200, 256, 0, stream>>>(x, wqT, qkv_b, buf1);
    dwconv_kernel<<<BB * NN, 256, 0, stream>>>(buf1, wposT, pos_b, buf2);
    entropy_kernel<<<NHEADS * BB * NRT, 256, 0, stream>>>(buf2, ent);
    gate_kernel<<<BB * NHEADS, 256, 0, stream>>>(ent, g1w, g1b, g2w, g2b, keep);
    sparse_attn_kernel<<<NHEADS * BB * NRT, 256, 0, stream>>>(buf2, keep, oh);
    proj_kernel<<<BB * 200, 256, 0, stream>>>(oh, wpT, proj_b, out);
}